// Round 4
// baseline (506.421 us; speedup 1.0000x reference)
//
#include <hip/hip_runtime.h>

#define N_USERS 60000
#define N_ITEMS 40000
#define N_TOTAL 100000
#define EMB 64
#define LN_EPS 1e-5f

#define KPS 128                                  // keys (dest rows) per super-bucket
#define KSH 7                                    // log2(KPS)
#define NSUP ((N_TOTAL + KPS - 1) / KPS)         // 782
#define EPB 4096                                 // edges per build_l1 block
#define TR_ROWS 32                               // rows per transform block
#define XPITCH 68                                // x-tile pitch (floats)
#define CAP 2048                                 // edges per LDS sort chunk
#define SPT 512                                  // spmm_fused threads (8 waves)

// bf16 helpers (exact shift for bf16->f32; RNE for f32->bf16)
__device__ __forceinline__ float bf2f(unsigned short h)
{ return __uint_as_float(((unsigned)h) << 16); }
__device__ __forceinline__ unsigned short f2bf(float f)
{
    unsigned u = __float_as_uint(f);
    return (unsigned short)((u + 0x7FFFu + ((u >> 16) & 1u)) >> 16);
}

// ---------------------------------------------------------------------------
// ego2[r,:] = c * filt[r] * (x[r,:] @ W) + x[r,:]   (bf16 output)
__global__ void transform_tile(const float* __restrict__ x,
                               const float* __restrict__ w_uu,
                               const float* __restrict__ filt_uu,
                               const float* __restrict__ par_uu,
                               const float* __restrict__ w_ii,
                               const float* __restrict__ filt_ii,
                               const float* __restrict__ par_ii,
                               unsigned short* __restrict__ out)
{
    __shared__ float Wls[EMB * EMB];             // 16 KB
    __shared__ float xs[TR_ROWS * XPITCH];       // 8.7 KB
    const int tid = threadIdx.x;
    const int r0 = blockIdx.x * TR_ROWS;
    const int itm = (r0 >= N_USERS);             // uniform per block
    const float* W  = itm ? w_ii : w_uu;
    const float* fb = itm ? filt_ii : filt_uu;
    const int foff  = itm ? N_USERS : 0;
    const float c   = itm ? par_ii[0] * par_ii[1] : par_uu[0] * par_uu[1];

    for (int i = tid; i < EMB * EMB / 4; i += 256)
        ((float4*)Wls)[i] = ((const float4*)W)[i];
    for (int i = tid; i < TR_ROWS * 16; i += 256) {
        const float4 v = ((const float4*)x)[r0 * 16 + i];
        *(float4*)&xs[(i >> 4) * XPITCH + (i & 15) * 4] = v;
    }
    __syncthreads();

    const int lane = tid & 63;
    const int wv = tid >> 6;
    const int rg = lane >> 4;
    const int j  = lane & 15;

#pragma unroll
    for (int it = 0; it < 2; ++it) {
        const int rl = wv * 8 + it * 4 + rg;
        const int row = r0 + rl;
        float4 acc = make_float4(0.f, 0.f, 0.f, 0.f);
#pragma unroll 8
        for (int k = 0; k < EMB; ++k) {
            const float xb = xs[rl * XPITCH + k];
            const float4 w4 = *(const float4*)&Wls[k * EMB + 4 * j];
            acc.x += xb * w4.x; acc.y += xb * w4.y;
            acc.z += xb * w4.z; acc.w += xb * w4.w;
        }
        const float cf = c * fb[row - foff];
        const float4 xv = *(const float4*)&xs[rl * XPITCH + 4 * j];
        ushort4 o;
        o.x = f2bf(cf * acc.x + xv.x);
        o.y = f2bf(cf * acc.y + xv.y);
        o.z = f2bf(cf * acc.z + xv.z);
        o.w = f2bf(cf * acc.w + xv.w);
        *(ushort4*)&out[(size_t)row * EMB + 4 * j] = o;
    }
}

// ---------------------------------------------------------------------------
// Super-bucket histograms for BOTH orderings. LDS-local then merge.
__global__ void hist_sup(const int* __restrict__ rows,
                         const int* __restrict__ cols,
                         int* __restrict__ cnt_r,
                         int* __restrict__ cnt_c, int nnz)
{
    __shared__ int hr[NSUP], hc[NSUP];
    const int tid = threadIdx.x;
    for (int i = tid; i < NSUP; i += 256) { hr[i] = 0; hc[i] = 0; }
    __syncthreads();
    for (int e = blockIdx.x * 256 + tid; e < nnz; e += gridDim.x * 256) {
        atomicAdd(&hr[rows[e] >> KSH], 1);
        atomicAdd(&hc[cols[e] >> KSH], 1);
    }
    __syncthreads();
    for (int i = tid; i < NSUP; i += 256) {
        if (hr[i]) atomicAdd(&cnt_r[i], hr[i]);
        if (hc[i]) atomicAdd(&cnt_c[i], hc[i]);
    }
}

// Exclusive scan of the NSUP counters (NSUP <= 1024). grid=2: blk0=cols, 1=rows.
__global__ void scan_sup(const int* __restrict__ cnt_c, int* __restrict__ base_c,
                         int* __restrict__ cur_c,
                         const int* __restrict__ cnt_r, int* __restrict__ base_r,
                         int* __restrict__ cur_r)
{
    const int* cnt = blockIdx.x ? cnt_r : cnt_c;
    int* base = blockIdx.x ? base_r : base_c;
    int* cur  = blockIdx.x ? cur_r  : cur_c;
    __shared__ int wsum[16];
    const int i = threadIdx.x;                   // 1024 threads = 16 waves
    const int lane = i & 63;
    const int wv = i >> 6;
    const int v = (i < NSUP) ? cnt[i] : 0;
    int incl = v;
#pragma unroll
    for (int off = 1; off < 64; off <<= 1) {
        const int t = __shfl_up(incl, off, 64);
        if (lane >= off) incl += t;
    }
    if (lane == 63) wsum[wv] = incl;
    __syncthreads();
    if (i == 0) {
        int run = 0;
#pragma unroll
        for (int w = 0; w < 16; ++w) { const int t = wsum[w]; wsum[w] = run; run += t; }
        base[NSUP] = run;
    }
    __syncthreads();
    const int excl = wsum[wv] + incl - v;
    if (i < NSUP) { base[i] = excl; cur[i] = excl; }
}

// ---------------------------------------------------------------------------
// Level 1: group a 4096-edge chunk by super-bucket in LDS, reserve global
// space per (block, sup) with one atomic, stream grouped bursts out.
// Payload: other(17b) | keylow7 << 20.  (round-1/2 proven at NSUP=782)
__global__ void __launch_bounds__(256, 1)
build_l1(const int* __restrict__ key,
         const int* __restrict__ other,
         const float* __restrict__ vals,
         int* __restrict__ cursor,
         int2* __restrict__ pairs1, int nnz)
{
    __shared__ int2 stage[EPB];                  // 32 KB
    __shared__ unsigned short sg[EPB];           // 8 KB
    __shared__ int hist[NSUP];                   // becomes sexcl after scan
    __shared__ int gbase[NSUP];
    __shared__ int lcur[NSUP];
    __shared__ int wsum[4];

    const int tid = threadIdx.x;
    const int e0 = blockIdx.x * EPB;
    const int ecnt = min(EPB, nnz - e0);

    for (int i = tid; i < NSUP; i += 256) hist[i] = 0;
    __syncthreads();

    int myk[16], myo[16];
    float myv[16];
#pragma unroll
    for (int i = 0; i < 16; ++i) {
        const int s = tid + i * 256;
        if (s < ecnt) {
            const int e = e0 + s;
            myk[i] = key[e]; myo[i] = other[e]; myv[i] = vals[e];
            atomicAdd(&hist[myk[i] >> KSH], 1);
        } else myk[i] = -1;
    }
    __syncthreads();

    // exclusive scan of hist[0..NSUP): thread t owns entries [4t, 4t+4)
    {
        const int lane = tid & 63;
        const int wv = tid >> 6;
        int loc[4]; int tsum = 0;
#pragma unroll
        for (int u = 0; u < 4; ++u) {
            const int idx = tid * 4 + u;
            const int v = (idx < NSUP) ? hist[idx] : 0;
            loc[u] = tsum; tsum += v;
        }
        int incl = tsum;
#pragma unroll
        for (int off = 1; off < 64; off <<= 1) {
            const int t = __shfl_up(incl, off, 64);
            if (lane >= off) incl += t;
        }
        if (lane == 63) wsum[wv] = incl;
        __syncthreads();
        int woff = 0;
        for (int w = 0; w < wv; ++w) woff += wsum[w];
        const int texcl = woff + incl - tsum;
#pragma unroll
        for (int u = 0; u < 4; ++u) {
            const int idx = tid * 4 + u;
            if (idx < NSUP) {
                const int v = hist[idx];
                const int e = texcl + loc[u];
                lcur[idx] = e;
                gbase[idx] = v ? atomicAdd(&cursor[idx], v) : 0;
                hist[idx] = e;                   // hist now holds sexcl
            }
        }
    }
    __syncthreads();

#pragma unroll
    for (int i = 0; i < 16; ++i) {
        if (myk[i] >= 0) {
            const int g = myk[i] >> KSH;
            const int s = atomicAdd(&lcur[g], 1);
            stage[s] = make_int2(myo[i] | ((myk[i] & (KPS - 1)) << 20),
                                 __float_as_int(myv[i]));
            sg[s] = (unsigned short)g;
        }
    }
    __syncthreads();

    for (int s = tid; s < ecnt; s += 256) {
        const int g = sg[s];
        pairs1[gbase[g] + (s - hist[g])] = stage[s];
    }
}

// ---------------------------------------------------------------------------
// Fused LDS counting-sort + register pull. One 512-thread block per 128-row
// super-bucket (782 blocks, 33.5 KB LDS -> 4 blocks/CU, whole grid
// co-resident). Chunks of CAP edges: stage -> int-atomic hist -> wave-0 scan
// -> LDS scatter -> per-group register pull (16-lane group owns 4 rows; acc
// persists across chunks). Next chunk's pairs are prefetched into REGISTERS
// before the consume phase so the global loads overlap the gather.
// (Round-2 lesson: no LDS FP atomics — wave64 ds_add_f32 ~260 cy/instr.
//  Round-3 lesson: 196 blocks / 62 KB LDS left the machine latency-bound at
//  32% occupancy; this re-tile is the fix.)
template <bool LN>
__global__ void __launch_bounds__(SPT, 8)
spmm_fused(const int* __restrict__ base,
           const int2* __restrict__ pairs,
           const unsigned short* __restrict__ src,
           const float* __restrict__ ego,
           const float* __restrict__ gamma,
           const float* __restrict__ beta,
           unsigned short* __restrict__ dstb,
           float* __restrict__ dstf)
{
    __shared__ int2 stage[CAP];                  // 16 KB
    __shared__ int2 sorted[CAP];                 // 16 KB
    __shared__ int cnt[KPS];                     // 512 B
    __shared__ int kbase[KPS];                   // 512 B
    __shared__ int kcur[KPS];                    // 512 B

    const int tid = threadIdx.x;
    const int sup = blockIdx.x;
    const int beg = base[sup];
    const int end = base[sup + 1];
    const int g = tid >> 4;                      // 32 groups of 16 lanes
    const int l = tid & 15;

    float4 acc[4];
#pragma unroll
    for (int i = 0; i < 4; ++i) acc[i] = make_float4(0.f, 0.f, 0.f, 0.f);

    if (tid < KPS) cnt[tid] = 0;
    __syncthreads();

    int c0 = beg;
    int csz = min(CAP, end - c0);
    for (int i = tid; i < csz; i += SPT) {
        const int2 v = pairs[c0 + i];
        stage[i] = v;
        atomicAdd(&cnt[(v.x >> 20) & (KPS - 1)], 1);
    }
    __syncthreads();

    while (csz > 0) {
        // ---- scan of 128 counters by wave 0 (lane owns 2 keys) -----------
        if (tid < 64) {
            const int ca = cnt[tid * 2];
            const int cb = cnt[tid * 2 + 1];
            const int tsum = ca + cb;
            int incl = tsum;
#pragma unroll
            for (int off = 1; off < 64; off <<= 1) {
                const int t = __shfl_up(incl, off, 64);
                if (tid >= off) incl += t;
            }
            const int run = incl - tsum;
            kbase[tid * 2] = run;       kcur[tid * 2] = run;
            kbase[tid * 2 + 1] = run + ca; kcur[tid * 2 + 1] = run + ca;
            cnt[tid * 2] = 0; cnt[tid * 2 + 1] = 0;   // ready for next hist
        }
        __syncthreads();

        // ---- counting-sort scatter (int LDS atomics: fast path) ----------
        for (int i = tid; i < csz; i += SPT) {
            const int2 v = stage[i];
            const int pos = atomicAdd(&kcur[(v.x >> 20) & (KPS - 1)], 1);
            sorted[pos] = v;
        }
        __syncthreads();

        // ---- prefetch next chunk to regs, consume, then write stage ------
        const int nc0 = c0 + csz;
        const int ncsz = min(CAP, end - nc0);

        int2 pre[CAP / SPT];
        int npre = 0;
        for (int i = tid; i < ncsz; i += SPT) pre[npre++] = pairs[nc0 + i];

#pragma unroll
        for (int rr = 0; rr < 4; ++rr) {
            const int k = g * 4 + rr;
            int j = kbase[k];
            const int e = kcur[k];               // == end of key's run
            float4 a = acc[rr];
            for (; j + 4 <= e; j += 4) {
                const int2 p0 = sorted[j];
                const int2 p1 = sorted[j + 1];
                const int2 p2 = sorted[j + 2];
                const int2 p3 = sorted[j + 3];
                const ushort4 s0 = ((const ushort4*)(src + (size_t)(p0.x & 0x1FFFF) * EMB))[l];
                const ushort4 s1 = ((const ushort4*)(src + (size_t)(p1.x & 0x1FFFF) * EMB))[l];
                const ushort4 s2 = ((const ushort4*)(src + (size_t)(p2.x & 0x1FFFF) * EMB))[l];
                const ushort4 s3 = ((const ushort4*)(src + (size_t)(p3.x & 0x1FFFF) * EMB))[l];
                const float v0 = __int_as_float(p0.y);
                const float v1 = __int_as_float(p1.y);
                const float v2 = __int_as_float(p2.y);
                const float v3 = __int_as_float(p3.y);
                a.x += v0 * bf2f(s0.x); a.y += v0 * bf2f(s0.y);
                a.z += v0 * bf2f(s0.z); a.w += v0 * bf2f(s0.w);
                a.x += v1 * bf2f(s1.x); a.y += v1 * bf2f(s1.y);
                a.z += v1 * bf2f(s1.z); a.w += v1 * bf2f(s1.w);
                a.x += v2 * bf2f(s2.x); a.y += v2 * bf2f(s2.y);
                a.z += v2 * bf2f(s2.z); a.w += v2 * bf2f(s2.w);
                a.x += v3 * bf2f(s3.x); a.y += v3 * bf2f(s3.y);
                a.z += v3 * bf2f(s3.z); a.w += v3 * bf2f(s3.w);
            }
            for (; j < e; ++j) {
                const int2 p = sorted[j];
                const ushort4 s = ((const ushort4*)(src + (size_t)(p.x & 0x1FFFF) * EMB))[l];
                const float v = __int_as_float(p.y);
                a.x += v * bf2f(s.x); a.y += v * bf2f(s.y);
                a.z += v * bf2f(s.z); a.w += v * bf2f(s.w);
            }
            acc[rr] = a;
        }

#pragma unroll
        for (int u = 0; u < CAP / SPT; ++u) {
            if (u < npre) {
                const int2 v = pre[u];
                stage[tid + u * SPT] = v;
                atomicAdd(&cnt[(v.x >> 20) & (KPS - 1)], 1);
            }
        }
        c0 = nc0; csz = ncsz;
        __syncthreads();
    }

    // ---- epilogue -------------------------------------------------------
    const int r0 = sup * KPS + g * 4;
    if (!LN) {
#pragma unroll
        for (int rr = 0; rr < 4; ++rr) {
            const int row = r0 + rr;
            if (row < N_TOTAL) {
                ushort4 o;
                o.x = f2bf(acc[rr].x); o.y = f2bf(acc[rr].y);
                o.z = f2bf(acc[rr].z); o.w = f2bf(acc[rr].w);
                ((ushort4*)dstb)[(size_t)row * 16 + l] = o;
            }
        }
    } else {
        const float4 gm = ((const float4*)gamma)[l];
        const float4 bt = ((const float4*)beta)[l];
#pragma unroll
        for (int rr = 0; rr < 4; ++rr) {
            const int row = r0 + rr;
            const float4 a = acc[rr];
            float s  = a.x + a.y + a.z + a.w;
            float s2 = a.x * a.x + a.y * a.y + a.z * a.z + a.w * a.w;
#pragma unroll
            for (int m = 1; m <= 8; m <<= 1) {   // reduce across the 16-lane group
                s  += __shfl_xor(s,  m, 64);
                s2 += __shfl_xor(s2, m, 64);
            }
            const float mu  = s * (1.0f / EMB);
            const float var = s2 * (1.0f / EMB) - mu * mu;
            const float inv = rsqrtf(var + LN_EPS);
            if (row < N_TOTAL) {
                const float4 eg = ((const float4*)(ego + (size_t)row * EMB))[l];
                float4 o;
                o.x = (a.x - mu) * inv * gm.x + bt.x + eg.x;
                o.y = (a.y - mu) * inv * gm.y + bt.y + eg.y;
                o.z = (a.z - mu) * inv * gm.z + bt.z + eg.z;
                o.w = (a.w - mu) * inv * gm.w + bt.w + eg.w;
                ((float4*)(dstf + (size_t)row * EMB))[l] = o;
            }
        }
    }
}

// ---------------------------------------------------------------------------
// Fallback (round-1) atomic scatter path, fp32, used only if ws too small.
__global__ void transform_kernel(const float* __restrict__ x,
                                 const float* __restrict__ W,
                                 const float* __restrict__ filt,
                                 const float* __restrict__ par,
                                 float* __restrict__ out, int nrows)
{
    __shared__ float Ws[EMB * EMB];
    const int tid = threadIdx.x;
    for (int i = tid; i < EMB * EMB; i += blockDim.x) Ws[i] = W[i];
    __syncthreads();
    const float c = par[0] * par[1];
    const int lane = tid & 63;
    const int wave = tid >> 6;
    const int r0 = blockIdx.x * 32;
    for (int rr = wave; rr < 32; rr += 4) {
        const int r = r0 + rr;
        if (r >= nrows) break;
        const float xv = x[(size_t)r * EMB + lane];
        float acc = 0.f;
#pragma unroll
        for (int k = 0; k < EMB; ++k) {
            const float xk = __shfl(xv, k, 64);
            acc += xk * Ws[k * EMB + lane];
        }
        out[(size_t)r * EMB + lane] = c * filt[r] * acc + xv;
    }
}

__global__ void spmm_scatter(const int* __restrict__ src_idx,
                             const int* __restrict__ dst_idx,
                             const float* __restrict__ vals,
                             const float* __restrict__ src,
                             float* __restrict__ dst, int nnz)
{
    const long long t = (long long)blockIdx.x * blockDim.x + threadIdx.x;
    const int e = (int)(t >> 4);
    const int l = (int)(t & 15);
    if (e >= nnz) return;
    const int s = src_idx[e];
    const int d = dst_idx[e];
    const float v = vals[e];
    const float4 xv = ((const float4*)(src + (size_t)s * EMB))[l];
    float* dp = dst + (size_t)d * EMB + l * 4;
    atomicAdd(dp + 0, v * xv.x);
    atomicAdd(dp + 1, v * xv.y);
    atomicAdd(dp + 2, v * xv.z);
    atomicAdd(dp + 3, v * xv.w);
}

__global__ void ln_residual(const float* y,
                            const float* __restrict__ ego,
                            const float* __restrict__ gamma,
                            const float* __restrict__ beta,
                            float* out, int nrows)
{
    const int lane = threadIdx.x & 63;
    const int wave = threadIdx.x >> 6;
    const int r = blockIdx.x * 4 + wave;
    if (r >= nrows) return;
    const float v = y[(size_t)r * EMB + lane];
    float s = v, s2 = v * v;
#pragma unroll
    for (int off = 32; off > 0; off >>= 1) {
        s  += __shfl_down(s,  off, 64);
        s2 += __shfl_down(s2, off, 64);
    }
    s  = __shfl(s,  0, 64);
    s2 = __shfl(s2, 0, 64);
    const float mu  = s * (1.0f / EMB);
    const float var = s2 * (1.0f / EMB) - mu * mu;
    const float inv = rsqrtf(var + LN_EPS);
    out[(size_t)r * EMB + lane] =
        (v - mu) * inv * gamma[lane] + beta[lane] + ego[(size_t)r * EMB + lane];
}

extern "C" void kernel_launch(void* const* d_in, const int* in_sizes, int n_in,
                              void* d_out, int out_size, void* d_ws, size_t ws_size,
                              hipStream_t stream)
{
    const float* ego     = (const float*)d_in[0];
    const int*   rows    = (const int*)  d_in[1];
    const int*   cols    = (const int*)  d_in[2];
    const float* vals    = (const float*)d_in[3];
    const float* w_uu    = (const float*)d_in[4];
    const float* filt_uu = (const float*)d_in[5];
    const float* par_uu  = (const float*)d_in[6];
    const float* w_ii    = (const float*)d_in[7];
    const float* filt_ii = (const float*)d_in[8];
    const float* par_ii  = (const float*)d_in[9];
    const float* gamma   = (const float*)d_in[10];
    const float* beta    = (const float*)d_in[11];
    float* out = (float*)d_out;
    const int nnz = in_sizes[1];

    const size_t emb_elems = (size_t)N_TOTAL * EMB;
    const size_t emb_bytes = emb_elems * sizeof(float);
    const size_t bf_bytes  = emb_elems * sizeof(unsigned short);

    // fast path use: 2 bf16 tables + ONE pairs array + counters  (~51.3 MB)
    const size_t need = 2 * bf_bytes + (size_t)nnz * sizeof(int2)
                        + (size_t)(6 * (NSUP + 1)) * sizeof(int);

    if (ws_size >= need) {
        // ---- fast path: sup-grouped edges + fused LDS-sort + reg pull ----
        unsigned short* ego2b = (unsigned short*)d_ws;    // 12.8 MB
        unsigned short* hb    = ego2b + emb_elems;        // 12.8 MB
        int2* pairs1 = (int2*)(hb + emb_elems);           // 25.6 MB
        int*  cnt_c  = (int*)(pairs1 + nnz);
        int*  cnt_r  = cnt_c + NSUP;
        int*  base_c = cnt_r + NSUP;
        int*  cur_c  = base_c + (NSUP + 1);
        int*  base_r = cur_c + NSUP;
        int*  cur_r  = base_r + (NSUP + 1);

        hipMemsetAsync(cnt_c, 0, 2 * NSUP * sizeof(int), stream);

        hist_sup<<<512, 256, 0, stream>>>(rows, cols, cnt_r, cnt_c, nnz);
        scan_sup<<<2, 1024, 0, stream>>>(cnt_c, base_c, cur_c,
                                         cnt_r, base_r, cur_r);

        transform_tile<<<N_TOTAL / TR_ROWS, 256, 0, stream>>>(
            ego, w_uu, filt_uu, par_uu, w_ii, filt_ii, par_ii, ego2b);

        const int l1b = (nnz + EPB - 1) / EPB;

        // Pass 1: key = col, payload = row.  h[c] = sum val*ego2[r]  (bf16)
        build_l1<<<l1b, 256, 0, stream>>>(cols, rows, vals, cur_c, pairs1, nnz);
        spmm_fused<false><<<NSUP, SPT, 0, stream>>>(
            base_c, pairs1, ego2b, nullptr, nullptr, nullptr, hb, nullptr);

        // Pass 2: key = row, payload = col.  out = LN(A h) + ego, fused.
        build_l1<<<l1b, 256, 0, stream>>>(rows, cols, vals, cur_r, pairs1, nnz);
        spmm_fused<true><<<NSUP, SPT, 0, stream>>>(
            base_r, pairs1, hb, ego, gamma, beta, nullptr, out);
    } else {
        // ---------------- fallback: atomic scatter (round-1, fp32) -------
        float* ego2 = (float*)d_ws;
        float* h    = ego2 + emb_elems;
        hipMemsetAsync(h,   0, emb_bytes, stream);
        hipMemsetAsync(out, 0, emb_bytes, stream);

        transform_kernel<<<(N_USERS + 31) / 32, 256, 0, stream>>>(
            ego, w_uu, filt_uu, par_uu, ego2, N_USERS);
        transform_kernel<<<(N_ITEMS + 31) / 32, 256, 0, stream>>>(
            ego + (size_t)N_USERS * EMB, w_ii, filt_ii, par_ii,
            ego2 + (size_t)N_USERS * EMB, N_ITEMS);

        const long long thr = (long long)nnz * 16;
        const int sblocks = (int)((thr + 255) / 256);
        spmm_scatter<<<sblocks, 256, 0, stream>>>(rows, cols, vals, ego2, h, nnz);
        spmm_scatter<<<sblocks, 256, 0, stream>>>(cols, rows, vals, h, out, nnz);

        const int rb = (N_TOTAL + 3) / 4;
        ln_residual<<<rb, 256, 0, stream>>>(out, ego, gamma, beta, out, N_TOTAL);
    }
}

// Round 5
// 431.705 us; speedup vs baseline: 1.1731x; 1.1731x over previous
//
#include <hip/hip_runtime.h>

#define N_USERS 60000
#define N_ITEMS 40000
#define N_TOTAL 100000
#define EMB 64
#define LN_EPS 1e-5f

#define KPS 128                                  // keys (dest rows) per super-bucket
#define KSH 7                                    // log2(KPS)
#define NSUP ((N_TOTAL + KPS - 1) / KPS)         // 782
#define EPB 4096                                 // edges per build_l1 block
#define BLT 512                                  // build_l1 threads (8 waves)
#define TR_ROWS 32                               // rows per transform block
#define XPITCH 68                                // x-tile pitch (floats)
#define CAP 2048                                 // edges per LDS sort chunk
#define SPT 512                                  // spmm_fused threads (8 waves)

// bf16 helpers (exact shift for bf16->f32; RNE for f32->bf16)
__device__ __forceinline__ float bf2f(unsigned short h)
{ return __uint_as_float(((unsigned)h) << 16); }
__device__ __forceinline__ unsigned short f2bf(float f)
{
    unsigned u = __float_as_uint(f);
    return (unsigned short)((u + 0x7FFFu + ((u >> 16) & 1u)) >> 16);
}

// ---------------------------------------------------------------------------
// ego2[r,:] = c * filt[r] * (x[r,:] @ W) + x[r,:]   (bf16 output)
__global__ void transform_tile(const float* __restrict__ x,
                               const float* __restrict__ w_uu,
                               const float* __restrict__ filt_uu,
                               const float* __restrict__ par_uu,
                               const float* __restrict__ w_ii,
                               const float* __restrict__ filt_ii,
                               const float* __restrict__ par_ii,
                               unsigned short* __restrict__ out)
{
    __shared__ float Wls[EMB * EMB];             // 16 KB
    __shared__ float xs[TR_ROWS * XPITCH];       // 8.7 KB
    const int tid = threadIdx.x;
    const int r0 = blockIdx.x * TR_ROWS;
    const int itm = (r0 >= N_USERS);             // uniform per block
    const float* W  = itm ? w_ii : w_uu;
    const float* fb = itm ? filt_ii : filt_uu;
    const int foff  = itm ? N_USERS : 0;
    const float c   = itm ? par_ii[0] * par_ii[1] : par_uu[0] * par_uu[1];

    for (int i = tid; i < EMB * EMB / 4; i += 256)
        ((float4*)Wls)[i] = ((const float4*)W)[i];
    for (int i = tid; i < TR_ROWS * 16; i += 256) {
        const float4 v = ((const float4*)x)[r0 * 16 + i];
        *(float4*)&xs[(i >> 4) * XPITCH + (i & 15) * 4] = v;
    }
    __syncthreads();

    const int lane = tid & 63;
    const int wv = tid >> 6;
    const int rg = lane >> 4;
    const int j  = lane & 15;

#pragma unroll
    for (int it = 0; it < 2; ++it) {
        const int rl = wv * 8 + it * 4 + rg;
        const int row = r0 + rl;
        float4 acc = make_float4(0.f, 0.f, 0.f, 0.f);
#pragma unroll 8
        for (int k = 0; k < EMB; ++k) {
            const float xb = xs[rl * XPITCH + k];
            const float4 w4 = *(const float4*)&Wls[k * EMB + 4 * j];
            acc.x += xb * w4.x; acc.y += xb * w4.y;
            acc.z += xb * w4.z; acc.w += xb * w4.w;
        }
        const float cf = c * fb[row - foff];
        const float4 xv = *(const float4*)&xs[rl * XPITCH + 4 * j];
        ushort4 o;
        o.x = f2bf(cf * acc.x + xv.x);
        o.y = f2bf(cf * acc.y + xv.y);
        o.z = f2bf(cf * acc.z + xv.z);
        o.w = f2bf(cf * acc.w + xv.w);
        *(ushort4*)&out[(size_t)row * EMB + 4 * j] = o;
    }
}

// ---------------------------------------------------------------------------
// Super-bucket histograms for BOTH orderings. LDS-local then merge.
__global__ void hist_sup(const int* __restrict__ rows,
                         const int* __restrict__ cols,
                         int* __restrict__ cnt_r,
                         int* __restrict__ cnt_c, int nnz)
{
    __shared__ int hr[NSUP], hc[NSUP];
    const int tid = threadIdx.x;
    for (int i = tid; i < NSUP; i += 256) { hr[i] = 0; hc[i] = 0; }
    __syncthreads();
    for (int e = blockIdx.x * 256 + tid; e < nnz; e += gridDim.x * 256) {
        atomicAdd(&hr[rows[e] >> KSH], 1);
        atomicAdd(&hc[cols[e] >> KSH], 1);
    }
    __syncthreads();
    for (int i = tid; i < NSUP; i += 256) {
        if (hr[i]) atomicAdd(&cnt_r[i], hr[i]);
        if (hc[i]) atomicAdd(&cnt_c[i], hc[i]);
    }
}

// Exclusive scan of the NSUP counters (NSUP <= 1024). grid=2: blk0=cols, 1=rows.
__global__ void scan_sup(const int* __restrict__ cnt_c, int* __restrict__ base_c,
                         int* __restrict__ cur_c,
                         const int* __restrict__ cnt_r, int* __restrict__ base_r,
                         int* __restrict__ cur_r)
{
    const int* cnt = blockIdx.x ? cnt_r : cnt_c;
    int* base = blockIdx.x ? base_r : base_c;
    int* cur  = blockIdx.x ? cur_r  : cur_c;
    __shared__ int wsum[16];
    const int i = threadIdx.x;                   // 1024 threads = 16 waves
    const int lane = i & 63;
    const int wv = i >> 6;
    const int v = (i < NSUP) ? cnt[i] : 0;
    int incl = v;
#pragma unroll
    for (int off = 1; off < 64; off <<= 1) {
        const int t = __shfl_up(incl, off, 64);
        if (lane >= off) incl += t;
    }
    if (lane == 63) wsum[wv] = incl;
    __syncthreads();
    if (i == 0) {
        int run = 0;
#pragma unroll
        for (int w = 0; w < 16; ++w) { const int t = wsum[w]; wsum[w] = run; run += t; }
        base[NSUP] = run;
    }
    __syncthreads();
    const int excl = wsum[wv] + incl - v;
    if (i < NSUP) { base[i] = excl; cur[i] = excl; }
}

// ---------------------------------------------------------------------------
// Level 1: group a 4096-edge chunk by super-bucket in LDS, reserve global
// space per (block, sup) with one atomic, stream grouped bursts out.
// Payload: other(17b) | keylow7 << 20.
// Round-4 lesson: at 256 threads this was latency-bound (Occ 29%, VALU 2.8%,
// 110 us vs ~10 us traffic floor). 512 threads halves the serial atomic
// chains; launch_bounds(512,6) -> 3 blocks/CU = 24 waves/CU, and the
// 782-block grid fits ~one co-resident round (768 slots).
__global__ void __launch_bounds__(BLT, 6)
build_l1(const int* __restrict__ key,
         const int* __restrict__ other,
         const float* __restrict__ vals,
         int* __restrict__ cursor,
         int2* __restrict__ pairs1, int nnz)
{
    __shared__ int2 stage[EPB];                  // 32 KB
    __shared__ unsigned short sg[EPB];           // 8 KB
    __shared__ int hist[NSUP];                   // becomes sexcl after scan
    __shared__ int gbase[NSUP];
    __shared__ int lcur[NSUP];
    __shared__ int wsum[8];

    const int tid = threadIdx.x;
    const int e0 = blockIdx.x * EPB;
    const int ecnt = min(EPB, nnz - e0);

    for (int i = tid; i < NSUP; i += BLT) hist[i] = 0;
    __syncthreads();

    int myk[EPB / BLT], myo[EPB / BLT];
    float myv[EPB / BLT];
#pragma unroll
    for (int i = 0; i < EPB / BLT; ++i) {
        const int s = tid + i * BLT;
        if (s < ecnt) {
            const int e = e0 + s;
            myk[i] = key[e]; myo[i] = other[e]; myv[i] = vals[e];
            atomicAdd(&hist[myk[i] >> KSH], 1);
        } else myk[i] = -1;
    }
    __syncthreads();

    // exclusive scan of hist[0..NSUP): thread t owns entries 2t, 2t+1
    {
        const int lane = tid & 63;
        const int wv = tid >> 6;                 // 0..7
        const int i0 = tid * 2;
        const int va = (i0     < NSUP) ? hist[i0]     : 0;
        const int vb = (i0 + 1 < NSUP) ? hist[i0 + 1] : 0;
        const int tsum = va + vb;
        int incl = tsum;
#pragma unroll
        for (int off = 1; off < 64; off <<= 1) {
            const int t = __shfl_up(incl, off, 64);
            if (lane >= off) incl += t;
        }
        if (lane == 63) wsum[wv] = incl;
        __syncthreads();
        int woff = 0;
        for (int w = 0; w < wv; ++w) woff += wsum[w];
        const int excl = woff + incl - tsum;
        if (i0 < NSUP) {
            lcur[i0] = excl;
            gbase[i0] = va ? atomicAdd(&cursor[i0], va) : 0;
            hist[i0] = excl;                     // hist now holds sexcl
        }
        if (i0 + 1 < NSUP) {
            lcur[i0 + 1] = excl + va;
            gbase[i0 + 1] = vb ? atomicAdd(&cursor[i0 + 1], vb) : 0;
            hist[i0 + 1] = excl + va;
        }
    }
    __syncthreads();

#pragma unroll
    for (int i = 0; i < EPB / BLT; ++i) {
        if (myk[i] >= 0) {
            const int g = myk[i] >> KSH;
            const int s = atomicAdd(&lcur[g], 1);
            stage[s] = make_int2(myo[i] | ((myk[i] & (KPS - 1)) << 20),
                                 __float_as_int(myv[i]));
            sg[s] = (unsigned short)g;
        }
    }
    __syncthreads();

    for (int s = tid; s < ecnt; s += BLT) {
        const int g = sg[s];
        pairs1[gbase[g] + (s - hist[g])] = stage[s];
    }
}

// ---------------------------------------------------------------------------
// Fused LDS counting-sort + register pull. One 512-thread block per 128-row
// super-bucket (782 blocks, 33.5 KB LDS, launch_bounds(512,6) -> 3 blocks/CU
// = 24 waves/CU with the whole grid ~co-resident). Chunks of CAP edges:
// stage -> int-atomic hist -> wave-0 scan -> LDS scatter -> per-group
// register pull (16-lane group owns 4 rows; acc persists across chunks).
// Round-3-proven inner loop (round-4's register prefetch + waves-per-EU=8
// VGPR cap removed: suspected spill regression).
// (Round-2 lesson: no LDS FP atomics — wave64 ds_add_f32 ~260 cy/instr.)
template <bool LN>
__global__ void __launch_bounds__(SPT, 6)
spmm_fused(const int* __restrict__ base,
           const int2* __restrict__ pairs,
           const unsigned short* __restrict__ src,
           const float* __restrict__ ego,
           const float* __restrict__ gamma,
           const float* __restrict__ beta,
           unsigned short* __restrict__ dstb,
           float* __restrict__ dstf)
{
    __shared__ int2 stage[CAP];                  // 16 KB
    __shared__ int2 sorted[CAP];                 // 16 KB
    __shared__ int cnt[KPS];                     // 512 B
    __shared__ int kbase[KPS];                   // 512 B
    __shared__ int kcur[KPS];                    // 512 B

    const int tid = threadIdx.x;
    const int sup = blockIdx.x;
    const int beg = base[sup];
    const int end = base[sup + 1];
    const int g = tid >> 4;                      // 32 groups of 16 lanes
    const int l = tid & 15;

    float4 acc[4];
#pragma unroll
    for (int i = 0; i < 4; ++i) acc[i] = make_float4(0.f, 0.f, 0.f, 0.f);

    if (tid < KPS) cnt[tid] = 0;
    __syncthreads();

    int c0 = beg;
    int csz = min(CAP, end - c0);
    for (int i = tid; i < csz; i += SPT) {
        const int2 v = pairs[c0 + i];
        stage[i] = v;
        atomicAdd(&cnt[(v.x >> 20) & (KPS - 1)], 1);
    }
    __syncthreads();

    while (csz > 0) {
        // ---- scan of 128 counters by wave 0 (lane owns 2 keys) -----------
        if (tid < 64) {
            const int ca = cnt[tid * 2];
            const int cb = cnt[tid * 2 + 1];
            const int tsum = ca + cb;
            int incl = tsum;
#pragma unroll
            for (int off = 1; off < 64; off <<= 1) {
                const int t = __shfl_up(incl, off, 64);
                if (tid >= off) incl += t;
            }
            const int run = incl - tsum;
            kbase[tid * 2] = run;          kcur[tid * 2] = run;
            kbase[tid * 2 + 1] = run + ca; kcur[tid * 2 + 1] = run + ca;
            cnt[tid * 2] = 0; cnt[tid * 2 + 1] = 0;   // ready for next hist
        }
        __syncthreads();

        // ---- counting-sort scatter (int LDS atomics: fast path) ----------
        for (int i = tid; i < csz; i += SPT) {
            const int2 v = stage[i];
            const int pos = atomicAdd(&kcur[(v.x >> 20) & (KPS - 1)], 1);
            sorted[pos] = v;
        }
        __syncthreads();

        // ---- consume (register pull) + stage next chunk ------------------
        const int nc0 = c0 + csz;
        const int ncsz = min(CAP, end - nc0);

#pragma unroll
        for (int rr = 0; rr < 4; ++rr) {
            const int k = g * 4 + rr;
            int j = kbase[k];
            const int e = kcur[k];               // == end of key's run
            float4 a = acc[rr];
            for (; j + 4 <= e; j += 4) {
                const int2 p0 = sorted[j];
                const int2 p1 = sorted[j + 1];
                const int2 p2 = sorted[j + 2];
                const int2 p3 = sorted[j + 3];
                const ushort4 s0 = ((const ushort4*)(src + (size_t)(p0.x & 0x1FFFF) * EMB))[l];
                const ushort4 s1 = ((const ushort4*)(src + (size_t)(p1.x & 0x1FFFF) * EMB))[l];
                const ushort4 s2 = ((const ushort4*)(src + (size_t)(p2.x & 0x1FFFF) * EMB))[l];
                const ushort4 s3 = ((const ushort4*)(src + (size_t)(p3.x & 0x1FFFF) * EMB))[l];
                const float v0 = __int_as_float(p0.y);
                const float v1 = __int_as_float(p1.y);
                const float v2 = __int_as_float(p2.y);
                const float v3 = __int_as_float(p3.y);
                a.x += v0 * bf2f(s0.x); a.y += v0 * bf2f(s0.y);
                a.z += v0 * bf2f(s0.z); a.w += v0 * bf2f(s0.w);
                a.x += v1 * bf2f(s1.x); a.y += v1 * bf2f(s1.y);
                a.z += v1 * bf2f(s1.z); a.w += v1 * bf2f(s1.w);
                a.x += v2 * bf2f(s2.x); a.y += v2 * bf2f(s2.y);
                a.z += v2 * bf2f(s2.z); a.w += v2 * bf2f(s2.w);
                a.x += v3 * bf2f(s3.x); a.y += v3 * bf2f(s3.y);
                a.z += v3 * bf2f(s3.z); a.w += v3 * bf2f(s3.w);
            }
            for (; j < e; ++j) {
                const int2 p = sorted[j];
                const ushort4 s = ((const ushort4*)(src + (size_t)(p.x & 0x1FFFF) * EMB))[l];
                const float v = __int_as_float(p.y);
                a.x += v * bf2f(s.x); a.y += v * bf2f(s.y);
                a.z += v * bf2f(s.z); a.w += v * bf2f(s.w);
            }
            acc[rr] = a;
        }

        for (int i = tid; i < ncsz; i += SPT) {
            const int2 v = pairs[nc0 + i];
            stage[i] = v;
            atomicAdd(&cnt[(v.x >> 20) & (KPS - 1)], 1);
        }
        c0 = nc0; csz = ncsz;
        __syncthreads();
    }

    // ---- epilogue -------------------------------------------------------
    const int r0 = sup * KPS + g * 4;
    if (!LN) {
#pragma unroll
        for (int rr = 0; rr < 4; ++rr) {
            const int row = r0 + rr;
            if (row < N_TOTAL) {
                ushort4 o;
                o.x = f2bf(acc[rr].x); o.y = f2bf(acc[rr].y);
                o.z = f2bf(acc[rr].z); o.w = f2bf(acc[rr].w);
                ((ushort4*)dstb)[(size_t)row * 16 + l] = o;
            }
        }
    } else {
        const float4 gm = ((const float4*)gamma)[l];
        const float4 bt = ((const float4*)beta)[l];
#pragma unroll
        for (int rr = 0; rr < 4; ++rr) {
            const int row = r0 + rr;
            const float4 a = acc[rr];
            float s  = a.x + a.y + a.z + a.w;
            float s2 = a.x * a.x + a.y * a.y + a.z * a.z + a.w * a.w;
#pragma unroll
            for (int m = 1; m <= 8; m <<= 1) {   // reduce across the 16-lane group
                s  += __shfl_xor(s,  m, 64);
                s2 += __shfl_xor(s2, m, 64);
            }
            const float mu  = s * (1.0f / EMB);
            const float var = s2 * (1.0f / EMB) - mu * mu;
            const float inv = rsqrtf(var + LN_EPS);
            if (row < N_TOTAL) {
                const float4 eg = ((const float4*)(ego + (size_t)row * EMB))[l];
                float4 o;
                o.x = (a.x - mu) * inv * gm.x + bt.x + eg.x;
                o.y = (a.y - mu) * inv * gm.y + bt.y + eg.y;
                o.z = (a.z - mu) * inv * gm.z + bt.z + eg.z;
                o.w = (a.w - mu) * inv * gm.w + bt.w + eg.w;
                ((float4*)(dstf + (size_t)row * EMB))[l] = o;
            }
        }
    }
}

// ---------------------------------------------------------------------------
// Fallback (round-1) atomic scatter path, fp32, used only if ws too small.
__global__ void transform_kernel(const float* __restrict__ x,
                                 const float* __restrict__ W,
                                 const float* __restrict__ filt,
                                 const float* __restrict__ par,
                                 float* __restrict__ out, int nrows)
{
    __shared__ float Ws[EMB * EMB];
    const int tid = threadIdx.x;
    for (int i = tid; i < EMB * EMB; i += blockDim.x) Ws[i] = W[i];
    __syncthreads();
    const float c = par[0] * par[1];
    const int lane = tid & 63;
    const int wave = tid >> 6;
    const int r0 = blockIdx.x * 32;
    for (int rr = wave; rr < 32; rr += 4) {
        const int r = r0 + rr;
        if (r >= nrows) break;
        const float xv = x[(size_t)r * EMB + lane];
        float acc = 0.f;
#pragma unroll
        for (int k = 0; k < EMB; ++k) {
            const float xk = __shfl(xv, k, 64);
            acc += xk * Ws[k * EMB + lane];
        }
        out[(size_t)r * EMB + lane] = c * filt[r] * acc + xv;
    }
}

__global__ void spmm_scatter(const int* __restrict__ src_idx,
                             const int* __restrict__ dst_idx,
                             const float* __restrict__ vals,
                             const float* __restrict__ src,
                             float* __restrict__ dst, int nnz)
{
    const long long t = (long long)blockIdx.x * blockDim.x + threadIdx.x;
    const int e = (int)(t >> 4);
    const int l = (int)(t & 15);
    if (e >= nnz) return;
    const int s = src_idx[e];
    const int d = dst_idx[e];
    const float v = vals[e];
    const float4 xv = ((const float4*)(src + (size_t)s * EMB))[l];
    float* dp = dst + (size_t)d * EMB + l * 4;
    atomicAdd(dp + 0, v * xv.x);
    atomicAdd(dp + 1, v * xv.y);
    atomicAdd(dp + 2, v * xv.z);
    atomicAdd(dp + 3, v * xv.w);
}

__global__ void ln_residual(const float* y,
                            const float* __restrict__ ego,
                            const float* __restrict__ gamma,
                            const float* __restrict__ beta,
                            float* out, int nrows)
{
    const int lane = threadIdx.x & 63;
    const int wave = threadIdx.x >> 6;
    const int r = blockIdx.x * 4 + wave;
    if (r >= nrows) return;
    const float v = y[(size_t)r * EMB + lane];
    float s = v, s2 = v * v;
#pragma unroll
    for (int off = 32; off > 0; off >>= 1) {
        s  += __shfl_down(s,  off, 64);
        s2 += __shfl_down(s2, off, 64);
    }
    s  = __shfl(s,  0, 64);
    s2 = __shfl(s2, 0, 64);
    const float mu  = s * (1.0f / EMB);
    const float var = s2 * (1.0f / EMB) - mu * mu;
    const float inv = rsqrtf(var + LN_EPS);
    out[(size_t)r * EMB + lane] =
        (v - mu) * inv * gamma[lane] + beta[lane] + ego[(size_t)r * EMB + lane];
}

extern "C" void kernel_launch(void* const* d_in, const int* in_sizes, int n_in,
                              void* d_out, int out_size, void* d_ws, size_t ws_size,
                              hipStream_t stream)
{
    const float* ego     = (const float*)d_in[0];
    const int*   rows    = (const int*)  d_in[1];
    const int*   cols    = (const int*)  d_in[2];
    const float* vals    = (const float*)d_in[3];
    const float* w_uu    = (const float*)d_in[4];
    const float* filt_uu = (const float*)d_in[5];
    const float* par_uu  = (const float*)d_in[6];
    const float* w_ii    = (const float*)d_in[7];
    const float* filt_ii = (const float*)d_in[8];
    const float* par_ii  = (const float*)d_in[9];
    const float* gamma   = (const float*)d_in[10];
    const float* beta    = (const float*)d_in[11];
    float* out = (float*)d_out;
    const int nnz = in_sizes[1];

    const size_t emb_elems = (size_t)N_TOTAL * EMB;
    const size_t emb_bytes = emb_elems * sizeof(float);
    const size_t bf_bytes  = emb_elems * sizeof(unsigned short);

    // fast path use: 2 bf16 tables + ONE pairs array + counters  (~51.3 MB)
    const size_t need = 2 * bf_bytes + (size_t)nnz * sizeof(int2)
                        + (size_t)(6 * (NSUP + 1)) * sizeof(int);

    if (ws_size >= need) {
        // ---- fast path: sup-grouped edges + fused LDS-sort + reg pull ----
        unsigned short* ego2b = (unsigned short*)d_ws;    // 12.8 MB
        unsigned short* hb    = ego2b + emb_elems;        // 12.8 MB
        int2* pairs1 = (int2*)(hb + emb_elems);           // 25.6 MB
        int*  cnt_c  = (int*)(pairs1 + nnz);
        int*  cnt_r  = cnt_c + NSUP;
        int*  base_c = cnt_r + NSUP;
        int*  cur_c  = base_c + (NSUP + 1);
        int*  base_r = cur_c + NSUP;
        int*  cur_r  = base_r + (NSUP + 1);

        hipMemsetAsync(cnt_c, 0, 2 * NSUP * sizeof(int), stream);

        hist_sup<<<512, 256, 0, stream>>>(rows, cols, cnt_r, cnt_c, nnz);
        scan_sup<<<2, 1024, 0, stream>>>(cnt_c, base_c, cur_c,
                                         cnt_r, base_r, cur_r);

        transform_tile<<<N_TOTAL / TR_ROWS, 256, 0, stream>>>(
            ego, w_uu, filt_uu, par_uu, w_ii, filt_ii, par_ii, ego2b);

        const int l1b = (nnz + EPB - 1) / EPB;

        // Pass 1: key = col, payload = row.  h[c] = sum val*ego2[r]  (bf16)
        build_l1<<<l1b, BLT, 0, stream>>>(cols, rows, vals, cur_c, pairs1, nnz);
        spmm_fused<false><<<NSUP, SPT, 0, stream>>>(
            base_c, pairs1, ego2b, nullptr, nullptr, nullptr, hb, nullptr);

        // Pass 2: key = row, payload = col.  out = LN(A h) + ego, fused.
        build_l1<<<l1b, BLT, 0, stream>>>(rows, cols, vals, cur_r, pairs1, nnz);
        spmm_fused<true><<<NSUP, SPT, 0, stream>>>(
            base_r, pairs1, hb, ego, gamma, beta, nullptr, out);
    } else {
        // ---------------- fallback: atomic scatter (round-1, fp32) -------
        float* ego2 = (float*)d_ws;
        float* h    = ego2 + emb_elems;
        hipMemsetAsync(h,   0, emb_bytes, stream);
        hipMemsetAsync(out, 0, emb_bytes, stream);

        transform_kernel<<<(N_USERS + 31) / 32, 256, 0, stream>>>(
            ego, w_uu, filt_uu, par_uu, ego2, N_USERS);
        transform_kernel<<<(N_ITEMS + 31) / 32, 256, 0, stream>>>(
            ego + (size_t)N_USERS * EMB, w_ii, filt_ii, par_ii,
            ego2 + (size_t)N_USERS * EMB, N_ITEMS);

        const long long thr = (long long)nnz * 16;
        const int sblocks = (int)((thr + 255) / 256);
        spmm_scatter<<<sblocks, 256, 0, stream>>>(rows, cols, vals, ego2, h, nnz);
        spmm_scatter<<<sblocks, 256, 0, stream>>>(cols, rows, vals, h, out, nnz);

        const int rb = (N_TOTAL + 3) / 4;
        ln_residual<<<rb, 256, 0, stream>>>(out, ego, gamma, beta, out, N_TOTAL);
    }
}

// Round 6
// 405.822 us; speedup vs baseline: 1.2479x; 1.0638x over previous
//
#include <hip/hip_runtime.h>

#define N_USERS 60000
#define N_ITEMS 40000
#define N_TOTAL 100000
#define EMB 64
#define LN_EPS 1e-5f

#define KPS 128                                  // keys (dest rows) per super-bucket
#define KSH 7                                    // log2(KPS)
#define NSUP ((N_TOTAL + KPS - 1) / KPS)         // 782
#define EPB 4096                                 // edges per build block
#define BLT 512                                  // build threads (8 waves)
#define TR_ROWS 32                               // rows per transform block
#define XPITCH 68                                // x-tile pitch (floats)
#define CAP 2048                                 // edges per LDS sort chunk
#define SPT 512                                  // spmm_fused threads (8 waves)

// bf16 helpers (exact shift for bf16->f32; RNE for f32->bf16)
__device__ __forceinline__ float bf2f(unsigned short h)
{ return __uint_as_float(((unsigned)h) << 16); }
__device__ __forceinline__ unsigned short f2bf(float f)
{
    unsigned u = __float_as_uint(f);
    return (unsigned short)((u + 0x7FFFu + ((u >> 16) & 1u)) >> 16);
}

// ---------------------------------------------------------------------------
// ego2[r,:] = c * filt[r] * (x[r,:] @ W) + x[r,:]   (bf16 output)
__global__ void transform_tile(const float* __restrict__ x,
                               const float* __restrict__ w_uu,
                               const float* __restrict__ filt_uu,
                               const float* __restrict__ par_uu,
                               const float* __restrict__ w_ii,
                               const float* __restrict__ filt_ii,
                               const float* __restrict__ par_ii,
                               unsigned short* __restrict__ out)
{
    __shared__ float Wls[EMB * EMB];             // 16 KB
    __shared__ float xs[TR_ROWS * XPITCH];       // 8.7 KB
    const int tid = threadIdx.x;
    const int r0 = blockIdx.x * TR_ROWS;
    const int itm = (r0 >= N_USERS);             // uniform per block
    const float* W  = itm ? w_ii : w_uu;
    const float* fb = itm ? filt_ii : filt_uu;
    const int foff  = itm ? N_USERS : 0;
    const float c   = itm ? par_ii[0] * par_ii[1] : par_uu[0] * par_uu[1];

    for (int i = tid; i < EMB * EMB / 4; i += 256)
        ((float4*)Wls)[i] = ((const float4*)W)[i];
    for (int i = tid; i < TR_ROWS * 16; i += 256) {
        const float4 v = ((const float4*)x)[r0 * 16 + i];
        *(float4*)&xs[(i >> 4) * XPITCH + (i & 15) * 4] = v;
    }
    __syncthreads();

    const int lane = tid & 63;
    const int wv = tid >> 6;
    const int rg = lane >> 4;
    const int j  = lane & 15;

#pragma unroll
    for (int it = 0; it < 2; ++it) {
        const int rl = wv * 8 + it * 4 + rg;
        const int row = r0 + rl;
        float4 acc = make_float4(0.f, 0.f, 0.f, 0.f);
#pragma unroll 8
        for (int k = 0; k < EMB; ++k) {
            const float xb = xs[rl * XPITCH + k];
            const float4 w4 = *(const float4*)&Wls[k * EMB + 4 * j];
            acc.x += xb * w4.x; acc.y += xb * w4.y;
            acc.z += xb * w4.z; acc.w += xb * w4.w;
        }
        const float cf = c * fb[row - foff];
        const float4 xv = *(const float4*)&xs[rl * XPITCH + 4 * j];
        ushort4 o;
        o.x = f2bf(cf * acc.x + xv.x);
        o.y = f2bf(cf * acc.y + xv.y);
        o.z = f2bf(cf * acc.z + xv.z);
        o.w = f2bf(cf * acc.w + xv.w);
        *(ushort4*)&out[(size_t)row * EMB + 4 * j] = o;
    }
}

// ---------------------------------------------------------------------------
// Super-bucket histograms for BOTH orderings. LDS-local then merge.
__global__ void hist_sup(const int* __restrict__ rows,
                         const int* __restrict__ cols,
                         int* __restrict__ cnt_r,
                         int* __restrict__ cnt_c, int nnz)
{
    __shared__ int hr[NSUP], hc[NSUP];
    const int tid = threadIdx.x;
    for (int i = tid; i < NSUP; i += 256) { hr[i] = 0; hc[i] = 0; }
    __syncthreads();
    for (int e = blockIdx.x * 256 + tid; e < nnz; e += gridDim.x * 256) {
        atomicAdd(&hr[rows[e] >> KSH], 1);
        atomicAdd(&hc[cols[e] >> KSH], 1);
    }
    __syncthreads();
    for (int i = tid; i < NSUP; i += 256) {
        if (hr[i]) atomicAdd(&cnt_r[i], hr[i]);
        if (hc[i]) atomicAdd(&cnt_c[i], hc[i]);
    }
}

// Exclusive scan of the NSUP counters (NSUP <= 1024). grid=2: blk0=cols, 1=rows.
__global__ void scan_sup(const int* __restrict__ cnt_c, int* __restrict__ base_c,
                         int* __restrict__ cur_c,
                         const int* __restrict__ cnt_r, int* __restrict__ base_r,
                         int* __restrict__ cur_r)
{
    const int* cnt = blockIdx.x ? cnt_r : cnt_c;
    int* base = blockIdx.x ? base_r : base_c;
    int* cur  = blockIdx.x ? cur_r  : cur_c;
    __shared__ int wsum[16];
    const int i = threadIdx.x;                   // 1024 threads = 16 waves
    const int lane = i & 63;
    const int wv = i >> 6;
    const int v = (i < NSUP) ? cnt[i] : 0;
    int incl = v;
#pragma unroll
    for (int off = 1; off < 64; off <<= 1) {
        const int t = __shfl_up(incl, off, 64);
        if (lane >= off) incl += t;
    }
    if (lane == 63) wsum[wv] = incl;
    __syncthreads();
    if (i == 0) {
        int run = 0;
#pragma unroll
        for (int w = 0; w < 16; ++w) { const int t = wsum[w]; wsum[w] = run; run += t; }
        base[NSUP] = run;
    }
    __syncthreads();
    const int excl = wsum[wv] + incl - v;
    if (i < NSUP) { base[i] = excl; cur[i] = excl; }
}

// ---------------------------------------------------------------------------
// Fused dual-ordering grouping: one block loads 4096 (row,col,val) triples
// ONCE into registers, histograms BOTH orderings with interleaved independent
// LDS-atomic chains (2x ILP in the latency-critical phase), then runs
// scan -> scatter -> emit twice, reusing the 32 KB stage buffer.
// Payloads: C-order  row | (col&127)<<20 ;  R-order  col | (row&127)<<20.
// (Round-5: two separate 512-thread builds ~70 us each; fusing removes one
//  input read + one dispatch ramp.)
__global__ void __launch_bounds__(BLT, 3)
build_both(const int* __restrict__ rows,
           const int* __restrict__ cols,
           const float* __restrict__ vals,
           int* __restrict__ cur_c, int2* __restrict__ pairs_c,
           int* __restrict__ cur_r, int2* __restrict__ pairs_r, int nnz)
{
    __shared__ int2 stage[EPB];                  // 32 KB
    __shared__ unsigned short sg[EPB];           // 8 KB
    __shared__ int hist_c[NSUP];                 // counts -> sexcl_c
    __shared__ int hist_r[NSUP];                 // counts -> sexcl_r
    __shared__ int gbase[NSUP];
    __shared__ int lcur[NSUP];
    __shared__ int wsum[8];

    const int tid = threadIdx.x;
    const int e0 = blockIdx.x * EPB;
    const int ecnt = min(EPB, nnz - e0);

    for (int i = tid; i < NSUP; i += BLT) { hist_c[i] = 0; hist_r[i] = 0; }
    __syncthreads();

    int myr[EPB / BLT], myc[EPB / BLT];
    float myv[EPB / BLT];
#pragma unroll
    for (int i = 0; i < EPB / BLT; ++i) {
        const int s = tid + i * BLT;
        if (s < ecnt) {
            const int e = e0 + s;
            myr[i] = rows[e]; myc[i] = cols[e]; myv[i] = vals[e];
            atomicAdd(&hist_c[myc[i] >> KSH], 1);   // two independent chains
            atomicAdd(&hist_r[myr[i] >> KSH], 1);
        } else myr[i] = -1;
    }
    __syncthreads();

    // ---- two passes: p=0 keyed by col -> pairs_c, p=1 keyed by row -------
#pragma unroll 1
    for (int p = 0; p < 2; ++p) {
        int* hist = p ? hist_r : hist_c;
        int* gcur = p ? cur_r  : cur_c;
        int2* out = p ? pairs_r : pairs_c;

        // exclusive scan of hist[0..NSUP): thread t owns entries 2t, 2t+1
        {
            const int lane = tid & 63;
            const int wv = tid >> 6;             // 0..7
            const int i0 = tid * 2;
            const int va = (i0     < NSUP) ? hist[i0]     : 0;
            const int vb = (i0 + 1 < NSUP) ? hist[i0 + 1] : 0;
            const int tsum = va + vb;
            int incl = tsum;
#pragma unroll
            for (int off = 1; off < 64; off <<= 1) {
                const int t = __shfl_up(incl, off, 64);
                if (lane >= off) incl += t;
            }
            if (lane == 63) wsum[wv] = incl;
            __syncthreads();
            int woff = 0;
            for (int w = 0; w < wv; ++w) woff += wsum[w];
            const int excl = woff + incl - tsum;
            if (i0 < NSUP) {
                lcur[i0] = excl;
                gbase[i0] = va ? atomicAdd(&gcur[i0], va) : 0;
                hist[i0] = excl;                 // hist now holds sexcl
            }
            if (i0 + 1 < NSUP) {
                lcur[i0 + 1] = excl + va;
                gbase[i0 + 1] = vb ? atomicAdd(&gcur[i0 + 1], vb) : 0;
                hist[i0 + 1] = excl + va;
            }
        }
        __syncthreads();

        // scatter into stage, grouped by this ordering's super-bucket
#pragma unroll
        for (int i = 0; i < EPB / BLT; ++i) {
            if (myr[i] >= 0) {
                const int key   = p ? myr[i] : myc[i];
                const int other = p ? myc[i] : myr[i];
                const int g = key >> KSH;
                const int s = atomicAdd(&lcur[g], 1);
                stage[s] = make_int2(other | ((key & (KPS - 1)) << 20),
                                     __float_as_int(myv[i]));
                sg[s] = (unsigned short)g;
            }
        }
        __syncthreads();

        // emit grouped bursts
        for (int s = tid; s < ecnt; s += BLT) {
            const int g = sg[s];
            out[gbase[g] + (s - hist[g])] = stage[s];
        }
        __syncthreads();                         // stage/gbase/lcur reuse
    }
}

// ---------------------------------------------------------------------------
// Fused LDS counting-sort + register pull. One 512-thread block per 128-row
// super-bucket (782 blocks, 33.5 KB LDS). Chunks of CAP edges: stage ->
// int-atomic hist -> wave-0 scan -> LDS scatter -> per-group register pull
// (16-lane group owns 4 rows; acc persists across chunks). 8/4/1 unroll
// ladder in the consume loop for memory-level parallelism (round-0 proven).
// (Round-2 lesson: no LDS FP atomics — wave64 ds_add_f32 ~260 cy/instr.)
template <bool LN>
__global__ void __launch_bounds__(SPT, 6)
spmm_fused(const int* __restrict__ base,
           const int2* __restrict__ pairs,
           const unsigned short* __restrict__ src,
           const float* __restrict__ ego,
           const float* __restrict__ gamma,
           const float* __restrict__ beta,
           unsigned short* __restrict__ dstb,
           float* __restrict__ dstf)
{
    __shared__ int2 stage[CAP];                  // 16 KB
    __shared__ int2 sorted[CAP];                 // 16 KB
    __shared__ int cnt[KPS];                     // 512 B
    __shared__ int kbase[KPS];                   // 512 B
    __shared__ int kcur[KPS];                    // 512 B

    const int tid = threadIdx.x;
    const int sup = blockIdx.x;
    const int beg = base[sup];
    const int end = base[sup + 1];
    const int g = tid >> 4;                      // 32 groups of 16 lanes
    const int l = tid & 15;

    float4 acc[4];
#pragma unroll
    for (int i = 0; i < 4; ++i) acc[i] = make_float4(0.f, 0.f, 0.f, 0.f);

    if (tid < KPS) cnt[tid] = 0;
    __syncthreads();

    int c0 = beg;
    int csz = min(CAP, end - c0);
    for (int i = tid; i < csz; i += SPT) {
        const int2 v = pairs[c0 + i];
        stage[i] = v;
        atomicAdd(&cnt[(v.x >> 20) & (KPS - 1)], 1);
    }
    __syncthreads();

    while (csz > 0) {
        // ---- scan of 128 counters by wave 0 (lane owns 2 keys) -----------
        if (tid < 64) {
            const int ca = cnt[tid * 2];
            const int cb = cnt[tid * 2 + 1];
            const int tsum = ca + cb;
            int incl = tsum;
#pragma unroll
            for (int off = 1; off < 64; off <<= 1) {
                const int t = __shfl_up(incl, off, 64);
                if (tid >= off) incl += t;
            }
            const int run = incl - tsum;
            kbase[tid * 2] = run;          kcur[tid * 2] = run;
            kbase[tid * 2 + 1] = run + ca; kcur[tid * 2 + 1] = run + ca;
            cnt[tid * 2] = 0; cnt[tid * 2 + 1] = 0;   // ready for next hist
        }
        __syncthreads();

        // ---- counting-sort scatter (int LDS atomics: fast path) ----------
        for (int i = tid; i < csz; i += SPT) {
            const int2 v = stage[i];
            const int pos = atomicAdd(&kcur[(v.x >> 20) & (KPS - 1)], 1);
            sorted[pos] = v;
        }
        __syncthreads();

        // ---- consume (register pull, 8/4/1 ladder) + stage next chunk ----
        const int nc0 = c0 + csz;
        const int ncsz = min(CAP, end - nc0);

#pragma unroll
        for (int rr = 0; rr < 4; ++rr) {
            const int k = g * 4 + rr;
            int j = kbase[k];
            const int e = kcur[k];               // == end of key's run
            float4 a = acc[rr];
            for (; j + 8 <= e; j += 8) {
                int2 p[8]; ushort4 s[8];
#pragma unroll
                for (int u = 0; u < 8; ++u) p[u] = sorted[j + u];
#pragma unroll
                for (int u = 0; u < 8; ++u)
                    s[u] = ((const ushort4*)(src + (size_t)(p[u].x & 0x1FFFF) * EMB))[l];
#pragma unroll
                for (int u = 0; u < 8; ++u) {
                    const float v = __int_as_float(p[u].y);
                    a.x += v * bf2f(s[u].x); a.y += v * bf2f(s[u].y);
                    a.z += v * bf2f(s[u].z); a.w += v * bf2f(s[u].w);
                }
            }
            for (; j + 4 <= e; j += 4) {
                int2 p[4]; ushort4 s[4];
#pragma unroll
                for (int u = 0; u < 4; ++u) p[u] = sorted[j + u];
#pragma unroll
                for (int u = 0; u < 4; ++u)
                    s[u] = ((const ushort4*)(src + (size_t)(p[u].x & 0x1FFFF) * EMB))[l];
#pragma unroll
                for (int u = 0; u < 4; ++u) {
                    const float v = __int_as_float(p[u].y);
                    a.x += v * bf2f(s[u].x); a.y += v * bf2f(s[u].y);
                    a.z += v * bf2f(s[u].z); a.w += v * bf2f(s[u].w);
                }
            }
            for (; j < e; ++j) {
                const int2 p = sorted[j];
                const ushort4 s = ((const ushort4*)(src + (size_t)(p.x & 0x1FFFF) * EMB))[l];
                const float v = __int_as_float(p.y);
                a.x += v * bf2f(s.x); a.y += v * bf2f(s.y);
                a.z += v * bf2f(s.z); a.w += v * bf2f(s.w);
            }
            acc[rr] = a;
        }

        for (int i = tid; i < ncsz; i += SPT) {
            const int2 v = pairs[nc0 + i];
            stage[i] = v;
            atomicAdd(&cnt[(v.x >> 20) & (KPS - 1)], 1);
        }
        c0 = nc0; csz = ncsz;
        __syncthreads();
    }

    // ---- epilogue -------------------------------------------------------
    const int r0 = sup * KPS + g * 4;
    if (!LN) {
#pragma unroll
        for (int rr = 0; rr < 4; ++rr) {
            const int row = r0 + rr;
            if (row < N_TOTAL) {
                ushort4 o;
                o.x = f2bf(acc[rr].x); o.y = f2bf(acc[rr].y);
                o.z = f2bf(acc[rr].z); o.w = f2bf(acc[rr].w);
                ((ushort4*)dstb)[(size_t)row * 16 + l] = o;
            }
        }
    } else {
        const float4 gm = ((const float4*)gamma)[l];
        const float4 bt = ((const float4*)beta)[l];
#pragma unroll
        for (int rr = 0; rr < 4; ++rr) {
            const int row = r0 + rr;
            const float4 a = acc[rr];
            float s  = a.x + a.y + a.z + a.w;
            float s2 = a.x * a.x + a.y * a.y + a.z * a.z + a.w * a.w;
#pragma unroll
            for (int m = 1; m <= 8; m <<= 1) {   // reduce across the 16-lane group
                s  += __shfl_xor(s,  m, 64);
                s2 += __shfl_xor(s2, m, 64);
            }
            const float mu  = s * (1.0f / EMB);
            const float var = s2 * (1.0f / EMB) - mu * mu;
            const float inv = rsqrtf(var + LN_EPS);
            if (row < N_TOTAL) {
                const float4 eg = ((const float4*)(ego + (size_t)row * EMB))[l];
                float4 o;
                o.x = (a.x - mu) * inv * gm.x + bt.x + eg.x;
                o.y = (a.y - mu) * inv * gm.y + bt.y + eg.y;
                o.z = (a.z - mu) * inv * gm.z + bt.z + eg.z;
                o.w = (a.w - mu) * inv * gm.w + bt.w + eg.w;
                ((float4*)(dstf + (size_t)row * EMB))[l] = o;
            }
        }
    }
}

// ---------------------------------------------------------------------------
// Fallback (round-1) atomic scatter path, fp32, used only if ws too small.
__global__ void transform_kernel(const float* __restrict__ x,
                                 const float* __restrict__ W,
                                 const float* __restrict__ filt,
                                 const float* __restrict__ par,
                                 float* __restrict__ out, int nrows)
{
    __shared__ float Ws[EMB * EMB];
    const int tid = threadIdx.x;
    for (int i = tid; i < EMB * EMB; i += blockDim.x) Ws[i] = W[i];
    __syncthreads();
    const float c = par[0] * par[1];
    const int lane = tid & 63;
    const int wave = tid >> 6;
    const int r0 = blockIdx.x * 32;
    for (int rr = wave; rr < 32; rr += 4) {
        const int r = r0 + rr;
        if (r >= nrows) break;
        const float xv = x[(size_t)r * EMB + lane];
        float acc = 0.f;
#pragma unroll
        for (int k = 0; k < EMB; ++k) {
            const float xk = __shfl(xv, k, 64);
            acc += xk * Ws[k * EMB + lane];
        }
        out[(size_t)r * EMB + lane] = c * filt[r] * acc + xv;
    }
}

__global__ void spmm_scatter(const int* __restrict__ src_idx,
                             const int* __restrict__ dst_idx,
                             const float* __restrict__ vals,
                             const float* __restrict__ src,
                             float* __restrict__ dst, int nnz)
{
    const long long t = (long long)blockIdx.x * blockDim.x + threadIdx.x;
    const int e = (int)(t >> 4);
    const int l = (int)(t & 15);
    if (e >= nnz) return;
    const int s = src_idx[e];
    const int d = dst_idx[e];
    const float v = vals[e];
    const float4 xv = ((const float4*)(src + (size_t)s * EMB))[l];
    float* dp = dst + (size_t)d * EMB + l * 4;
    atomicAdd(dp + 0, v * xv.x);
    atomicAdd(dp + 1, v * xv.y);
    atomicAdd(dp + 2, v * xv.z);
    atomicAdd(dp + 3, v * xv.w);
}

__global__ void ln_residual(const float* y,
                            const float* __restrict__ ego,
                            const float* __restrict__ gamma,
                            const float* __restrict__ beta,
                            float* out, int nrows)
{
    const int lane = threadIdx.x & 63;
    const int wave = threadIdx.x >> 6;
    const int r = blockIdx.x * 4 + wave;
    if (r >= nrows) return;
    const float v = y[(size_t)r * EMB + lane];
    float s = v, s2 = v * v;
#pragma unroll
    for (int off = 32; off > 0; off >>= 1) {
        s  += __shfl_down(s,  off, 64);
        s2 += __shfl_down(s2, off, 64);
    }
    s  = __shfl(s,  0, 64);
    s2 = __shfl(s2, 0, 64);
    const float mu  = s * (1.0f / EMB);
    const float var = s2 * (1.0f / EMB) - mu * mu;
    const float inv = rsqrtf(var + LN_EPS);
    out[(size_t)r * EMB + lane] =
        (v - mu) * inv * gamma[lane] + beta[lane] + ego[(size_t)r * EMB + lane];
}

extern "C" void kernel_launch(void* const* d_in, const int* in_sizes, int n_in,
                              void* d_out, int out_size, void* d_ws, size_t ws_size,
                              hipStream_t stream)
{
    const float* ego     = (const float*)d_in[0];
    const int*   rows    = (const int*)  d_in[1];
    const int*   cols    = (const int*)  d_in[2];
    const float* vals    = (const float*)d_in[3];
    const float* w_uu    = (const float*)d_in[4];
    const float* filt_uu = (const float*)d_in[5];
    const float* par_uu  = (const float*)d_in[6];
    const float* w_ii    = (const float*)d_in[7];
    const float* filt_ii = (const float*)d_in[8];
    const float* par_ii  = (const float*)d_in[9];
    const float* gamma   = (const float*)d_in[10];
    const float* beta    = (const float*)d_in[11];
    float* out = (float*)d_out;
    const int nnz = in_sizes[1];

    const size_t emb_elems = (size_t)N_TOTAL * EMB;
    const size_t emb_bytes = emb_elems * sizeof(float);
    const size_t bf_bytes  = emb_elems * sizeof(unsigned short);

    // fast path: 2 bf16 tables + TWO pairs arrays + counters (~77.0 MB,
    // equals the bound proven available in the original session)
    const size_t need = 2 * bf_bytes + 2 * (size_t)nnz * sizeof(int2)
                        + (size_t)(6 * (NSUP + 1)) * sizeof(int);

    if (ws_size >= need) {
        // ---- fast path: fused dual build + fused LDS-sort + reg pull -----
        unsigned short* ego2b = (unsigned short*)d_ws;    // 12.8 MB
        unsigned short* hb    = ego2b + emb_elems;        // 12.8 MB
        int2* pairs_c = (int2*)(hb + emb_elems);          // 25.6 MB
        int2* pairs_r = pairs_c + nnz;                    // 25.6 MB
        int*  cnt_c  = (int*)(pairs_r + nnz);
        int*  cnt_r  = cnt_c + NSUP;
        int*  base_c = cnt_r + NSUP;
        int*  cur_c  = base_c + (NSUP + 1);
        int*  base_r = cur_c + NSUP;
        int*  cur_r  = base_r + (NSUP + 1);

        hipMemsetAsync(cnt_c, 0, 2 * NSUP * sizeof(int), stream);

        hist_sup<<<512, 256, 0, stream>>>(rows, cols, cnt_r, cnt_c, nnz);
        scan_sup<<<2, 1024, 0, stream>>>(cnt_c, base_c, cur_c,
                                         cnt_r, base_r, cur_r);

        transform_tile<<<N_TOTAL / TR_ROWS, 256, 0, stream>>>(
            ego, w_uu, filt_uu, par_uu, w_ii, filt_ii, par_ii, ego2b);

        const int l1b = (nnz + EPB - 1) / EPB;
        build_both<<<l1b, BLT, 0, stream>>>(rows, cols, vals,
                                            cur_c, pairs_c, cur_r, pairs_r, nnz);

        // Pass 1: key = col, payload = row.  h[c] = sum val*ego2[r]  (bf16)
        spmm_fused<false><<<NSUP, SPT, 0, stream>>>(
            base_c, pairs_c, ego2b, nullptr, nullptr, nullptr, hb, nullptr);

        // Pass 2: key = row, payload = col.  out = LN(A h) + ego, fused.
        spmm_fused<true><<<NSUP, SPT, 0, stream>>>(
            base_r, pairs_r, hb, ego, gamma, beta, nullptr, out);
    } else {
        // ---------------- fallback: atomic scatter (round-1, fp32) -------
        float* ego2 = (float*)d_ws;
        float* h    = ego2 + emb_elems;
        hipMemsetAsync(h,   0, emb_bytes, stream);
        hipMemsetAsync(out, 0, emb_bytes, stream);

        transform_kernel<<<(N_USERS + 31) / 32, 256, 0, stream>>>(
            ego, w_uu, filt_uu, par_uu, ego2, N_USERS);
        transform_kernel<<<(N_ITEMS + 31) / 32, 256, 0, stream>>>(
            ego + (size_t)N_USERS * EMB, w_ii, filt_ii, par_ii,
            ego2 + (size_t)N_USERS * EMB, N_ITEMS);

        const long long thr = (long long)nnz * 16;
        const int sblocks = (int)((thr + 255) / 256);
        spmm_scatter<<<sblocks, 256, 0, stream>>>(rows, cols, vals, ego2, h, nnz);
        spmm_scatter<<<sblocks, 256, 0, stream>>>(cols, rows, vals, h, out, nnz);

        const int rb = (N_TOTAL + 3) / 4;
        ln_residual<<<rb, 256, 0, stream>>>(out, ego, gamma, beta, out, N_TOTAL);
    }
}